// Round 1
// baseline (59.977 us; speedup 1.0000x reference)
//
#include <hip/hip_runtime.h>
#include <math.h>

// Problem constants (from reference): B=32768, S=16, D=64
#define Bn 32768
#define Sn 16
#define Dn 64
#define NB 8            // batches staged per block
#define STRIDE 68       // padded LDS row stride in floats (16B-aligned, breaks pow2 banks)
#define THREADS 256

// Each block: stages NB batches of z1+z2 into LDS (fully coalesced float4),
// then 32 threads per batch compute the 16x16 distance matrix with a
// 2x4 register tile per thread.
__global__ __launch_bounds__(THREADS, 2)
void get_logit_mc_kernel(const float* __restrict__ z1,
                         const float* __restrict__ z2,
                         const float* __restrict__ pa,
                         const float* __restrict__ pb,
                         float* __restrict__ out) {
    __shared__ float zs[2][NB][Sn][STRIDE];   // [arr][batch][row][d-padded]

    const int t  = threadIdx.x;
    const int bb = blockIdx.x * NB;           // first global batch of this block

    // ---- stage: NB*2*16*64 floats = 4096 float4 per block, 16 per thread ----
    #pragma unroll
    for (int k = 0; k < 16; ++k) {
        int Q     = t + k * THREADS;          // 0..4095
        int batch = Q >> 9;                   // /512 (quads per batch: z1 256 + z2 256)
        int rem   = Q & 511;
        int arr   = rem >> 8;                 // 0 = z1, 1 = z2
        int e     = rem & 255;
        int row   = e >> 4;                   // 0..15
        int q     = e & 15;                   // d-quad 0..15
        const float* src = (arr ? z2 : z1) +
                           (((size_t)(bb + batch) * Sn + row) * Dn + q * 4);
        float4 v = *reinterpret_cast<const float4*>(src);
        *reinterpret_cast<float4*>(&zs[arr][batch][row][q * 4]) = v;
    }

    const float av = pa[0];
    const float bv = pb[0];

    __syncthreads();

    // ---- compute: thread = batch_local*32 + r*4 + c ----
    // rows {2r, 2r+1}, cols {4c .. 4c+3}
    const int bl = t >> 5;                    // 0..7  (batch within block)
    const int r  = (t >> 2) & 7;             // 0..7
    const int c  = t & 3;                     // 0..3

    float acc[2][4] = {{0.f,0.f,0.f,0.f},{0.f,0.f,0.f,0.f}};

    #pragma unroll
    for (int q = 0; q < 16; ++q) {
        float4 x0 = *reinterpret_cast<const float4*>(&zs[0][bl][2*r    ][q*4]);
        float4 x1 = *reinterpret_cast<const float4*>(&zs[0][bl][2*r + 1][q*4]);
        #pragma unroll
        for (int jj = 0; jj < 4; ++jj) {
            float4 y = *reinterpret_cast<const float4*>(&zs[1][bl][4*c + jj][q*4]);
            float d;
            d = x0.x - y.x; acc[0][jj] = fmaf(d, d, acc[0][jj]);
            d = x0.y - y.y; acc[0][jj] = fmaf(d, d, acc[0][jj]);
            d = x0.z - y.z; acc[0][jj] = fmaf(d, d, acc[0][jj]);
            d = x0.w - y.w; acc[0][jj] = fmaf(d, d, acc[0][jj]);
            d = x1.x - y.x; acc[1][jj] = fmaf(d, d, acc[1][jj]);
            d = x1.y - y.y; acc[1][jj] = fmaf(d, d, acc[1][jj]);
            d = x1.z - y.z; acc[1][jj] = fmaf(d, d, acc[1][jj]);
            d = x1.w - y.w; acc[1][jj] = fmaf(d, d, acc[1][jj]);
        }
    }

    // ---- epilogue: dist -> sigmoid -> clip -> coalesced float4 stores ----
    #pragma unroll
    for (int ii = 0; ii < 2; ++ii) {
        float4 o;
        float* po = &o.x;
        #pragma unroll
        for (int jj = 0; jj < 4; ++jj) {
            float dist = sqrtf(acc[ii][jj]);          // acc >= 0 by construction
            float x    = fmaf(dist, av, bv);
            float e    = __expf(-x);
            float sg   = 1.0f / (1.0f + e);
            sg = fminf(sg, 1.0f);
            sg = fmaxf(sg, 1e-8f);
            po[jj] = sg;
        }
        int i = 2*r + ii;
        float* dst = out + ((size_t)(bb + bl) * (Sn * Sn) + i * Sn + c * 4);
        *reinterpret_cast<float4*>(dst) = o;
    }
}

extern "C" void kernel_launch(void* const* d_in, const int* in_sizes, int n_in,
                              void* d_out, int out_size, void* d_ws, size_t ws_size,
                              hipStream_t stream) {
    const float* z1 = (const float*)d_in[0];
    const float* z2 = (const float*)d_in[1];
    const float* pa = (const float*)d_in[2];
    const float* pb = (const float*)d_in[3];
    float* out      = (float*)d_out;

    dim3 grid(Bn / NB);
    dim3 block(THREADS);
    hipLaunchKernelGGL(get_logit_mc_kernel, grid, block, 0, stream,
                       z1, z2, pa, pb, out);
}

// Round 2
// 52.606 us; speedup vs baseline: 1.1401x; 1.1401x over previous
//
#include <hip/hip_runtime.h>
#include <math.h>

// Problem constants (from reference): B=32768, S=16, D=64
#define Bn 32768
#define Sn 16
#define Dn 64
#define NB 2            // batches staged per block
#define STRIDE 68       // padded LDS row stride in floats (16B-aligned, 2-way banks max)
#define THREADS 128     // 64 threads per batch, each computes a 2x2 output tile

__global__ __launch_bounds__(THREADS, 4)
void get_logit_mc_kernel(const float* __restrict__ z1,
                         const float* __restrict__ z2,
                         const float* __restrict__ pa,
                         const float* __restrict__ pb,
                         float* __restrict__ out) {
    __shared__ float zs[2][NB][Sn][STRIDE];   // [arr][batch][row][d-padded] = 17408 B

    const int t  = threadIdx.x;
    const int bb = blockIdx.x * NB;           // first global batch of this block

    // ---- stage: NB*2*16*64 floats = 1024 float4 per block, 8 per thread ----
    #pragma unroll
    for (int k = 0; k < 8; ++k) {
        int Q     = t + k * THREADS;          // 0..1023
        int batch = Q >> 9;                   // /512 (quads per batch: z1 256 + z2 256)
        int rem   = Q & 511;
        int arr   = rem >> 8;                 // 0 = z1, 1 = z2
        int e     = rem & 255;
        int row   = e >> 4;                   // 0..15
        int q     = e & 15;                   // d-quad 0..15
        const float* src = (arr ? z2 : z1) +
                           (((size_t)(bb + batch) * Sn + row) * Dn + q * 4);
        float4 v = *reinterpret_cast<const float4*>(src);
        *reinterpret_cast<float4*>(&zs[arr][batch][row][q * 4]) = v;
    }

    const float av = pa[0];
    const float bv = pb[0];

    __syncthreads();

    // ---- compute: thread = batch_local*64 + r*8 + c ----
    // rows {2r, 2r+1}, cols {2c, 2c+1}
    const int bl = t >> 6;                    // 0..1  (batch within block; 1 wave per batch)
    const int r  = (t >> 3) & 7;              // 0..7
    const int c  = t & 7;                     // 0..7

    float acc[2][2] = {{0.f,0.f},{0.f,0.f}};

    #pragma unroll
    for (int q = 0; q < 16; ++q) {
        float4 x0 = *reinterpret_cast<const float4*>(&zs[0][bl][2*r    ][q*4]);
        float4 x1 = *reinterpret_cast<const float4*>(&zs[0][bl][2*r + 1][q*4]);
        #pragma unroll
        for (int jj = 0; jj < 2; ++jj) {
            float4 y = *reinterpret_cast<const float4*>(&zs[1][bl][2*c + jj][q*4]);
            float d;
            d = x0.x - y.x; acc[0][jj] = fmaf(d, d, acc[0][jj]);
            d = x0.y - y.y; acc[0][jj] = fmaf(d, d, acc[0][jj]);
            d = x0.z - y.z; acc[0][jj] = fmaf(d, d, acc[0][jj]);
            d = x0.w - y.w; acc[0][jj] = fmaf(d, d, acc[0][jj]);
            d = x1.x - y.x; acc[1][jj] = fmaf(d, d, acc[1][jj]);
            d = x1.y - y.y; acc[1][jj] = fmaf(d, d, acc[1][jj]);
            d = x1.z - y.z; acc[1][jj] = fmaf(d, d, acc[1][jj]);
            d = x1.w - y.w; acc[1][jj] = fmaf(d, d, acc[1][jj]);
        }
    }

    // ---- epilogue: dist -> sigmoid -> clip -> coalesced float2 stores ----
    #pragma unroll
    for (int ii = 0; ii < 2; ++ii) {
        float2 o;
        #pragma unroll
        for (int jj = 0; jj < 2; ++jj) {
            float dist = sqrtf(acc[ii][jj]);          // acc >= 0 by construction
            float x    = fmaf(dist, av, bv);
            float e    = __expf(-x);
            float sg   = 1.0f / (1.0f + e);
            sg = fminf(sg, 1.0f);
            sg = fmaxf(sg, 1e-8f);
            (&o.x)[jj] = sg;
        }
        int i = 2*r + ii;
        float* dst = out + ((size_t)(bb + bl) * (Sn * Sn) + i * Sn + c * 2);
        *reinterpret_cast<float2*>(dst) = o;
    }
}

extern "C" void kernel_launch(void* const* d_in, const int* in_sizes, int n_in,
                              void* d_out, int out_size, void* d_ws, size_t ws_size,
                              hipStream_t stream) {
    const float* z1 = (const float*)d_in[0];
    const float* z2 = (const float*)d_in[1];
    const float* pa = (const float*)d_in[2];
    const float* pb = (const float*)d_in[3];
    float* out      = (float*)d_out;

    dim3 grid(Bn / NB);
    dim3 block(THREADS);
    hipLaunchKernelGGL(get_logit_mc_kernel, grid, block, 0, stream,
                       z1, z2, pa, pb, out);
}